// Round 6
// baseline (425.558 us; speedup 1.0000x reference)
//
#include <hip/hip_runtime.h>
#include <hip/hip_bf16.h>
#include <cstdint>

typedef __bf16 bf16;
typedef __bf16 bf16x8 __attribute__((ext_vector_type(8)));
typedef __bf16 bf16x4 __attribute__((ext_vector_type(4)));
typedef float f32x4 __attribute__((ext_vector_type(4)));
typedef int i32x4 __attribute__((ext_vector_type(4)));

#define HIDC 96
#define CINC 192
#define EPSC 1e-5f

// wpack layout: 56 stages (28 offs x 2 halves) x 20480 B. Real payload per
// stage = 18 cix x 1024 B = 18432 B (+2048 B pad -> uniform 5x16B chunks per
// thread at 256 threads). cix = kc_local*6+ct, element =
//   W[off][k = (half*3+kc_local)*32 + (lane>>4)*8 + j][col = ct*16 + (lane&15)]
#define STG_B 20480
#define STG_ELEM 10240

// ---------------------------------------------------------------------------
// K0: repack W_conv [27][192][96] fp32 + W_lin [192][96] fp32 -> bf16 wpack.
// ---------------------------------------------------------------------------
__global__ void k_repack(const float* __restrict__ Wc, const float* __restrict__ Wl,
                         bf16* __restrict__ dst, int total) {
  int t = blockIdx.x * 256 + threadIdx.x;
  if (t >= total) return;              // total = 28*18432 real elements
  int off = t / 18432;
  int rem = t - off * 18432;
  int cix = rem >> 9;
  int lane = (rem >> 3) & 63;
  int j = rem & 7;
  int k = (cix / 6) * 32 + ((lane >> 4) << 3) + j;
  int col = (cix % 6) * 16 + (lane & 15);
  const float* src = (off < 27) ? (Wc + ((size_t)off * CINC + k) * HIDC + col)
                                : (Wl + (size_t)k * HIDC + col);
  int half = (cix >= 18) ? 1 : 0;
  size_t de = (size_t)(off * 2 + half) * STG_ELEM + (size_t)(rem - half * 9216);
  dst[de] = (bf16)(*src);
}

// ---------------------------------------------------------------------------
// Voxelize path: counting-sort + gather-mean (replaces 23M fp32 atomics).
// ---------------------------------------------------------------------------
__global__ void k_count(const int* __restrict__ seg, int* __restrict__ cnt, int Npts) {
  int t = blockIdx.x * 256 + threadIdx.x;
  if (t < Npts) atomicAdd(cnt + seg[t], 1);
}

__global__ void k_bsum(const int* __restrict__ cnt, int* __restrict__ bsum, int M) {
  __shared__ int sm[256];
  int i = blockIdx.x * 256 + threadIdx.x;
  sm[threadIdx.x] = (i < M) ? cnt[i] : 0;
  __syncthreads();
  for (int st = 128; st > 0; st >>= 1) {
    if (threadIdx.x < st) sm[threadIdx.x] += sm[threadIdx.x + st];
    __syncthreads();
  }
  if (threadIdx.x == 0) bsum[blockIdx.x] = sm[0];
}

// exclusive scan of nb (<=1024) block sums, in place. Shuffle-based:
// per-wave inclusive scan + 16-wave LDS fixup (2 barriers vs 20).
__global__ void k_bscan(int* __restrict__ bsum, int nb) {
  int i = threadIdx.x;
  int v = (i < nb) ? bsum[i] : 0;
  int x = v;
#pragma unroll
  for (int d = 1; d < 64; d <<= 1) {
    int t = __shfl_up(x, d);
    if ((i & 63) >= d) x += t;
  }
  __shared__ int wsum[16];
  if ((i & 63) == 63) wsum[i >> 6] = x;
  __syncthreads();
  if (i < 16) {
    int w = wsum[i];
    int y = w;
#pragma unroll
    for (int d = 1; d < 16; d <<= 1) {
      int t = __shfl_up(y, d, 16);
      if (i >= d) y += t;
    }
    wsum[i] = y - w;  // exclusive wave base
  }
  __syncthreads();
  if (i < nb) bsum[i] = (x - v) + wsum[i >> 6];
}

__global__ void k_ptr(const int* __restrict__ cnt, const int* __restrict__ bsum,
                      int* __restrict__ ptr, int* __restrict__ cursor, int M) {
  __shared__ int sm[256];
  int i = blockIdx.x * 256 + threadIdx.x;
  int v = (i < M) ? cnt[i] : 0;
  sm[threadIdx.x] = v;
  __syncthreads();
  for (int st = 1; st < 256; st <<= 1) {
    int t = (threadIdx.x >= st) ? sm[threadIdx.x - st] : 0;
    __syncthreads();
    sm[threadIdx.x] += t;
    __syncthreads();
  }
  if (i < M) {
    int e = bsum[blockIdx.x] + sm[threadIdx.x] - v;
    ptr[i] = e;
    cursor[i] = e;
  }
}

__global__ void k_scatter(const int* __restrict__ seg, int* __restrict__ cursor,
                          int* __restrict__ plist, int Npts) {
  int t = blockIdx.x * 256 + threadIdx.x;
  if (t < Npts) {
    int pos = atomicAdd(cursor + seg[t], 1);
    plist[pos] = t;
  }
}

// per (voxel, 4-channel group): mean of member point features -> bf16 vpad.
__global__ void k_gmean(const float* __restrict__ hid, const float* __restrict__ qry,
                        const int* __restrict__ ptr, const int* __restrict__ cnt,
                        const int* __restrict__ plist, bf16* __restrict__ vpad, int M) {
  int t = blockIdx.x * 256 + threadIdx.x;
  if (t >= (M + 1) * 48) return;
  int v = t / 48;
  int q = t - v * 48;
  f32x4 a = {0.f, 0.f, 0.f, 0.f};
  if (v < M) {
    int st = ptr[v], n = cnt[v];
    const float* base = (q < 24) ? (hid + q * 4) : (qry + (q - 24) * 4);
    for (int j = 0; j < n; j++) {
      int p = plist[st + j];
      a += *(const f32x4*)(base + (size_t)p * HIDC);
    }
    a *= (1.0f / (float)(n > 0 ? n : 1));
  }
  bf16x4 o;
#pragma unroll
  for (int j = 0; j < 4; j++) o[j] = (bf16)a[j];
  *(bf16x4*)(vpad + (size_t)v * CINC + q * 4) = o;
}

// ---------------------------------------------------------------------------
// K3: sparse conv — EXACT round-0 structure (best measured: 136us). 256 thr
// = 4 waves x 32 rows = 128 rows/block, plain stores. B double-buffered in
// LDS through a register staging buffer (breg) loaded a FULL stage ahead;
// A-fragments + nbr indices software-pipelined one stage ahead so the
// gather latency is covered by a whole stage of issue before the barrier's
// vmcnt(0) drain. One __syncthreads per stage (write->barrier->read; the
// next write to the same buffer is two barriers away). ONLY addition vs
// round 0: fused BN column stats in the epilogue (replaces k_bnstat's
// 37MB re-read; proven rounds 2-5).
// ---------------------------------------------------------------------------
__launch_bounds__(256, 3)
__global__ void k_conv(const bf16* __restrict__ vpad, const int* __restrict__ nbr,
                       const bf16* __restrict__ wpack, float* __restrict__ accbuf,
                       float* __restrict__ bnsum, int M, int nblk, int nper) {
  const int bx = (int)(blockIdx.x & 7) * nper + (int)(blockIdx.x >> 3);
  if (bx >= nblk) return;
  __shared__ bf16 Bb[2][STG_B / 2];  // 2 x 20KB
  const int tid = threadIdx.x;
  const int wave = tid >> 6;
  const int lane = tid & 63;
  const int m = lane & 15;
  const int quad = lane >> 4;
  const int rb = bx * 128 + wave * 32;

  f32x4 acc[2][6];
#pragma unroll
  for (int rt = 0; rt < 2; rt++)
#pragma unroll
    for (int ct = 0; ct < 6; ct++) {
      f32x4 z = {0.f, 0.f, 0.f, 0.f};
      acc[rt][ct] = z;
    }

  const char* wb = (const char*)wpack;
  i32x4 breg[5];
#pragma unroll
  for (int i = 0; i < 5; i++)
    breg[i] = *(const i32x4*)(wb + (size_t)(tid + 256 * i) * 16);

  // prologue: gidx for offset 0, A-frags for stage 0 (half0 -> kc 0..2)
  int gidx[2], gidx2[2];
#pragma unroll
  for (int rt = 0; rt < 2; rt++) {
    int r = rb + rt * 16 + m;
    gidx[rt] = (r < M) ? nbr[(size_t)r * 27] : M;
  }
  bf16x8 afn[2][3];
#pragma unroll
  for (int kc2 = 0; kc2 < 3; kc2++)
#pragma unroll
    for (int rt = 0; rt < 2; rt++)
      afn[rt][kc2] = *(const bf16x8*)(vpad + (size_t)gidx[rt] * CINC + kc2 * 32 + quad * 8);

  for (int s = 0; s < 54; s++) {
    const int buf = s & 1;
    {
      char* bbw = (char*)&Bb[buf][0];
#pragma unroll
      for (int i = 0; i < 5; i++)
        *(i32x4*)(bbw + (size_t)(tid + 256 * i) * 16) = breg[i];
    }
    __syncthreads();
    if (s < 53) {
      const char* src = wb + (size_t)(s + 1) * STG_B;
#pragma unroll
      for (int i = 0; i < 5; i++)
        breg[i] = *(const i32x4*)(src + (size_t)(tid + 256 * i) * 16);
    }
    // take the prefetched A-frags for this stage
    bf16x8 afc[2][3];
#pragma unroll
    for (int kc2 = 0; kc2 < 3; kc2++)
#pragma unroll
      for (int rt = 0; rt < 2; rt++) afc[rt][kc2] = afn[rt][kc2];

    const int half = s & 1;
    const int off = s >> 1;
    if (half == 0) {
      // prefetch nbr for off+1 (used one stage later)
      const int offn = off + 1;
#pragma unroll
      for (int rt = 0; rt < 2; rt++) {
        int r = rb + rt * 16 + m;
        gidx2[rt] = (r < M && offn < 27) ? nbr[(size_t)r * 27 + offn] : M;
      }
      // prefetch A for stage s+1 (half1 of same off -> kc 3..5, rows gidx)
      if (s < 53) {
#pragma unroll
        for (int kc2 = 0; kc2 < 3; kc2++)
#pragma unroll
          for (int rt = 0; rt < 2; rt++)
            afn[rt][kc2] = *(const bf16x8*)(vpad + (size_t)gidx[rt] * CINC +
                                            (kc2 + 3) * 32 + quad * 8);
      }
    } else {
      // prefetch A for stage s+1 (half0 of off+1 -> kc 0..2, rows gidx2)
      if (s < 53) {
#pragma unroll
        for (int kc2 = 0; kc2 < 3; kc2++)
#pragma unroll
          for (int rt = 0; rt < 2; rt++)
            afn[rt][kc2] = *(const bf16x8*)(vpad + (size_t)gidx2[rt] * CINC +
                                            kc2 * 32 + quad * 8);
      }
      gidx[0] = gidx2[0];
      gidx[1] = gidx2[1];
    }

    const char* bbr = (const char*)&Bb[buf][0];
#pragma unroll
    for (int kc2 = 0; kc2 < 3; kc2++) {
#pragma unroll
      for (int ct = 0; ct < 6; ct++) {
        bf16x8 bfm = *(const bf16x8*)(bbr + (size_t)(kc2 * 6 + ct) * 1024 + (size_t)lane * 16);
#pragma unroll
        for (int rt = 0; rt < 2; rt++)
          acc[rt][ct] = __builtin_amdgcn_mfma_f32_16x16x32_bf16(afc[rt][kc2], bfm, acc[rt][ct], 0, 0, 0);
      }
    }
  }

  // epilogue: plain stores (C layout: row = quad*4+rr, col = ct*16+m) with
  // fused BN column sums/sumsq (replaces k_bnstat's full accbuf re-read)
  float ps[6], pq[6];
#pragma unroll
  for (int ct = 0; ct < 6; ct++) { ps[ct] = 0.f; pq[ct] = 0.f; }
#pragma unroll
  for (int rt = 0; rt < 2; rt++) {
#pragma unroll
    for (int rr = 0; rr < 4; rr++) {
      const int r2 = rb + rt * 16 + quad * 4 + rr;
      if (r2 < M) {
        float* dst = accbuf + (size_t)r2 * HIDC + m;
#pragma unroll
        for (int ct = 0; ct < 6; ct++) {
          float v = acc[rt][ct][rr];
          dst[ct * 16] = v;
          ps[ct] += v;
          pq[ct] += v * v;
        }
      }
    }
  }
#pragma unroll
  for (int ct = 0; ct < 6; ct++) {
    float s1 = ps[ct], s2 = pq[ct];
    s1 += __shfl_xor(s1, 16);
    s2 += __shfl_xor(s2, 16);
    s1 += __shfl_xor(s1, 32);
    s2 += __shfl_xor(s2, 32);
    if (quad == 0) {
      atomicAdd(bnsum + ct * 16 + m, s1);
      atomicAdd(bnsum + 96 + ct * 16 + m, s2);
    }
  }
}

// ---------------------------------------------------------------------------
// K5: y = relu(acc*scale + shift) -> bf16 ypad, zero pad row M. BN finalize
// (scale/shift from raw sums) computed per block into LDS (k_bnfin folded in).
// ---------------------------------------------------------------------------
__global__ void k_bnapply(const float* __restrict__ accbuf, const float* __restrict__ bnsum,
                          const float* __restrict__ gamma, const float* __restrict__ beta,
                          bf16* __restrict__ ypad, int M) {
  __shared__ float ssc[96], ssh[96];
  if (threadIdx.x < 96) {
    int c = threadIdx.x;
    float inv = 1.0f / (float)M;
    float mu = bnsum[c] * inv;
    float var = fmaxf(bnsum[96 + c] * inv - mu * mu, 0.f);
    float sc = gamma[c] * rsqrtf(var + EPSC);
    ssc[c] = sc;
    ssh[c] = beta[c] - mu * sc;
  }
  __syncthreads();
  int t = blockIdx.x * 256 + threadIdx.x;
  if (t >= (M + 1) * 24) return;
  int v = t / 24;
  int g = t - v * 24;
  f32x4 y = {0.f, 0.f, 0.f, 0.f};
  if (v < M) {
    f32x4 a = *(const f32x4*)(accbuf + (size_t)v * HIDC + g * 4);
#pragma unroll
    for (int j = 0; j < 4; j++) y[j] = fmaxf(a[j] * ssc[g * 4 + j] + ssh[g * 4 + j], 0.f);
  }
  bf16x4 o;
#pragma unroll
  for (int j = 0; j < 4; j++) o[j] = (bf16)y[j];
  *(bf16x4*)(ypad + (size_t)v * HIDC + g * 4) = o;
}

// ---------------------------------------------------------------------------
// K6: lin = hx @ W_lin + b_lin (fp32 in, bf16 MFMA, bf16 out). LDS-free,
// 256 thr = 4 waves x 32 rows; B fragments direct from L2-resident wlpack
// (stage-padded layout: half = kc>=3).
// ---------------------------------------------------------------------------
__launch_bounds__(256, 4)
__global__ void k_linear(const float* __restrict__ hid, const float* __restrict__ qry,
                         const bf16* __restrict__ wlpack, const float* __restrict__ blin,
                         bf16* __restrict__ lin, int Npts) {
  const int tid = threadIdx.x;
  const int wave = tid >> 6;
  const int lane = tid & 63;
  const int m = lane & 15;
  const int quad = lane >> 4;
  const int rb = blockIdx.x * 128 + wave * 32;

  f32x4 acc[2][6];
#pragma unroll
  for (int rt = 0; rt < 2; rt++)
#pragma unroll
    for (int ct = 0; ct < 6; ct++) {
      f32x4 z = {0.f, 0.f, 0.f, 0.f};
      acc[rt][ct] = z;
    }

  int prow[2];
#pragma unroll
  for (int rt = 0; rt < 2; rt++) {
    int r = rb + rt * 16 + m;
    prow[rt] = (r < Npts) ? r : (Npts - 1);
  }
  const char* wp = (const char*)wlpack;
#pragma unroll
  for (int kc = 0; kc < 6; kc++) {
    const float* srcA = (kc < 3) ? (hid + kc * 32) : (qry + (kc - 3) * 32);
    bf16x8 af[2];
#pragma unroll
    for (int rt = 0; rt < 2; rt++) {
      const float* pA = srcA + (size_t)prow[rt] * HIDC + quad * 8;
      f32x4 lo = *(const f32x4*)pA;
      f32x4 hi = *(const f32x4*)(pA + 4);
#pragma unroll
      for (int j = 0; j < 4; j++) {
        af[rt][j] = (bf16)lo[j];
        af[rt][4 + j] = (bf16)hi[j];
      }
    }
    const int half = (kc >= 3) ? 1 : 0;
    const int kcl = kc - half * 3;
#pragma unroll
    for (int ct = 0; ct < 6; ct++) {
      bf16x8 bfm = *(const bf16x8*)(wp + (size_t)half * STG_B +
                                    (size_t)((kcl * 6 + ct) * 64 + lane) * 16);
#pragma unroll
      for (int rt = 0; rt < 2; rt++)
        acc[rt][ct] = __builtin_amdgcn_mfma_f32_16x16x32_bf16(af[rt], bfm, acc[rt][ct], 0, 0, 0);
    }
  }
  float bl[6];
#pragma unroll
  for (int ct = 0; ct < 6; ct++) bl[ct] = blin[ct * 16 + m];
#pragma unroll
  for (int rt = 0; rt < 2; rt++)
#pragma unroll
    for (int rr = 0; rr < 4; rr++) {
      const int r2 = rb + rt * 16 + quad * 4 + rr;
      if (r2 < Npts) {
        bf16* dst = lin + (size_t)r2 * HIDC + m;
#pragma unroll
        for (int ct = 0; ct < 6; ct++)
          dst[ct * 16] = (bf16)(acc[rt][ct][rr] + bl[ct]);
      }
    }
}

// ---------------------------------------------------------------------------
// K7: out = lin + sum_k w[p,k] * ypad[cidx[p,k]]  (8-channel groups)
// ---------------------------------------------------------------------------
__global__ void k_out(const bf16* __restrict__ lin, const bf16* __restrict__ ypad,
                      const float* __restrict__ cw, const int* __restrict__ cidx,
                      float* __restrict__ out, int Npts) {
  int t = blockIdx.x * 256 + threadIdx.x;
  if (t >= Npts * 12) return;
  int p = t / 12;
  int g = t - p * 12;
  float a[8];
  bf16x8 lv = *(const bf16x8*)(lin + (size_t)p * HIDC + g * 8);
#pragma unroll
  for (int j = 0; j < 8; j++) a[j] = (float)lv[j];
  f32x4 w0 = *(const f32x4*)(cw + (size_t)p * 8);
  f32x4 w1 = *(const f32x4*)(cw + (size_t)p * 8 + 4);
  const i32x4* cp = (const i32x4*)(cidx + (size_t)p * 8);
  i32x4 c0 = cp[0], c1 = cp[1];
#pragma unroll
  for (int k = 0; k < 8; k++) {
    int idx = (k < 4) ? c0[k] : c1[k - 4];
    float wk = (k < 4) ? w0[k] : w1[k - 4];
    bf16x8 yv = *(const bf16x8*)(ypad + (size_t)idx * HIDC + g * 8);
#pragma unroll
    for (int j = 0; j < 8; j++) a[j] += wk * (float)yv[j];
  }
  float* op = out + (size_t)p * HIDC + g * 8;
  f32x4 s0, s1;
#pragma unroll
  for (int j = 0; j < 4; j++) { s0[j] = a[j]; s1[j] = a[4 + j]; }
  *(f32x4*)op = s0;
  *(f32x4*)(op + 4) = s1;
}

// ---------------------------------------------------------------------------
extern "C" void kernel_launch(void* const* d_in, const int* in_sizes, int n_in,
                              void* d_out, int out_size, void* d_ws, size_t ws_size,
                              hipStream_t stream) {
  const float* hid = (const float*)d_in[0];
  const float* qry = (const float*)d_in[1];
  const float* Wc = (const float*)d_in[2];
  const float* gamma = (const float*)d_in[3];
  const float* beta = (const float*)d_in[4];
  const float* Wl = (const float*)d_in[5];
  const float* blin = (const float*)d_in[6];
  const float* cw = (const float*)d_in[7];
  const int* seg = (const int*)d_in[8];
  const int* nbr = (const int*)d_in[9];
  const int* cidx = (const int*)d_in[10];
  float* out = (float*)d_out;
  const int Npts = in_sizes[0] / HIDC;
  const int M = in_sizes[9] / 27;

  // ---- workspace layout ----
  // [cnt | bnsum]  <- single memset
  // region A: accbuf fp32 [M,96] (K3..K5) -> lin bf16 [N,96] (K6-K7) overlay
  // region B: vpad bf16 [M+1,192] (gmean..conv) -> ypad bf16 [M+1,96] overlay
  char* ws = (char*)d_ws;
  size_t cur = 0;
  auto alloc = [&](size_t b) { size_t o = cur; cur = (cur + b + 255) & ~(size_t)255; return o; };
  size_t o_cnt = alloc((size_t)M * 4);
  size_t o_bn = alloc(192 * 4);
  size_t zend = cur;  // memset range [0, zend): cnt + bnsum
  size_t o_ptr = alloc((size_t)M * 4);
  size_t o_cur = alloc((size_t)M * 4);
  size_t o_pl = alloc((size_t)Npts * 4);
  size_t o_bs = alloc(1024 * 4);
  size_t RA = (size_t)M * HIDC * 4;
  size_t needA = (size_t)Npts * HIDC * 2;
  if (needA > RA) RA = needA;
  size_t o_A = alloc(RA);
  size_t o_B = alloc((size_t)(M + 1) * CINC * 2);
  size_t o_wpack = alloc((size_t)56 * STG_B);
  (void)ws_size; (void)n_in; (void)out_size;

  int* cnt = (int*)(ws + o_cnt);
  float* bnsum = (float*)(ws + o_bn);
  int* ptr = (int*)(ws + o_ptr);
  int* cursor = (int*)(ws + o_cur);
  int* plist = (int*)(ws + o_pl);
  int* bsum = (int*)(ws + o_bs);
  float* accbuf = (float*)(ws + o_A);
  bf16* lin = (bf16*)(ws + o_A);
  bf16* vpad = (bf16*)(ws + o_B);
  bf16* ypad = (bf16*)(ws + o_B);
  bf16* wpack = (bf16*)(ws + o_wpack);
  bf16* wlpack = (bf16*)(ws + o_wpack + (size_t)54 * STG_B);

  // zero cnt + bnsum (adjacent at front; ws poisoned 0xAA each call)
  hipMemsetAsync(ws, 0, zend, stream);

  int totalRepack = 28 * 18432;
  k_repack<<<(totalRepack + 255) / 256, 256, 0, stream>>>(Wc, Wl, wpack, totalRepack);

  // voxelize: count -> scan -> scatter -> gather-mean
  int nb = (M + 255) / 256;
  k_count<<<(Npts + 255) / 256, 256, 0, stream>>>(seg, cnt, Npts);
  k_bsum<<<nb, 256, 0, stream>>>(cnt, bsum, M);
  k_bscan<<<1, 1024, 0, stream>>>(bsum, nb);
  k_ptr<<<nb, 256, 0, stream>>>(cnt, bsum, ptr, cursor, M);
  k_scatter<<<(Npts + 255) / 256, 256, 0, stream>>>(seg, cursor, plist, Npts);
  k_gmean<<<(((M + 1) * 48) + 255) / 256, 256, 0, stream>>>(hid, qry, ptr, cnt, plist, vpad, M);

  int nblk = (M + 127) / 128;
  int nper = (nblk + 7) / 8;
  k_conv<<<nper * 8, 256, 0, stream>>>(vpad, nbr, wpack, accbuf, bnsum, M, nblk, nper);
  k_bnapply<<<((M + 1) * 24 + 255) / 256, 256, 0, stream>>>(accbuf, bnsum, gamma, beta, ypad, M);
  k_linear<<<(Npts + 127) / 128, 256, 0, stream>>>(hid, qry, wlpack, blin, lin, Npts);
  k_out<<<(Npts * 12 + 255) / 256, 256, 0, stream>>>(lin, ypad, cw, cidx, out, Npts);
}

// Round 7
// 382.179 us; speedup vs baseline: 1.1135x; 1.1135x over previous
//
#include <hip/hip_runtime.h>
#include <hip/hip_bf16.h>
#include <cstdint>

typedef __bf16 bf16;
typedef __bf16 bf16x8 __attribute__((ext_vector_type(8)));
typedef __bf16 bf16x4 __attribute__((ext_vector_type(4)));
typedef float f32x4 __attribute__((ext_vector_type(4)));
typedef int i32x4 __attribute__((ext_vector_type(4)));

#define HIDC 96
#define CINC 192
#define EPSC 1e-5f

// wpack layout: 56 stages (28 offs x 2 halves) x 20480 B. Real payload per
// stage = 18 cix x 1024 B = 18432 B (+2048 B pad -> uniform 5x16B chunks per
// thread at 256 threads). cix = kc_local*6+ct, element =
//   W[off][k = (half*3+kc_local)*32 + (lane>>4)*8 + j][col = ct*16 + (lane&15)]
#define STG_B 20480
#define STG_ELEM 10240

// ---------------------------------------------------------------------------
// K0: repack W_conv [27][192][96] fp32 + W_lin [192][96] fp32 -> bf16 wpack.
// ---------------------------------------------------------------------------
__global__ void k_repack(const float* __restrict__ Wc, const float* __restrict__ Wl,
                         bf16* __restrict__ dst, int total) {
  int t = blockIdx.x * 256 + threadIdx.x;
  if (t >= total) return;              // total = 28*18432 real elements
  int off = t / 18432;
  int rem = t - off * 18432;
  int cix = rem >> 9;
  int lane = (rem >> 3) & 63;
  int j = rem & 7;
  int k = (cix / 6) * 32 + ((lane >> 4) << 3) + j;
  int col = (cix % 6) * 16 + (lane & 15);
  const float* src = (off < 27) ? (Wc + ((size_t)off * CINC + k) * HIDC + col)
                                : (Wl + (size_t)k * HIDC + col);
  int half = (cix >= 18) ? 1 : 0;
  size_t de = (size_t)(off * 2 + half) * STG_ELEM + (size_t)(rem - half * 9216);
  dst[de] = (bf16)(*src);
}

// ---------------------------------------------------------------------------
// Voxelize path: counting-sort + gather-mean (replaces 23M fp32 atomics).
// ---------------------------------------------------------------------------
__global__ void k_count(const int* __restrict__ seg, int* __restrict__ cnt, int Npts) {
  int t = blockIdx.x * 256 + threadIdx.x;
  if (t < Npts) atomicAdd(cnt + seg[t], 1);
}

__global__ void k_bsum(const int* __restrict__ cnt, int* __restrict__ bsum, int M) {
  __shared__ int sm[256];
  int i = blockIdx.x * 256 + threadIdx.x;
  sm[threadIdx.x] = (i < M) ? cnt[i] : 0;
  __syncthreads();
  for (int st = 128; st > 0; st >>= 1) {
    if (threadIdx.x < st) sm[threadIdx.x] += sm[threadIdx.x + st];
    __syncthreads();
  }
  if (threadIdx.x == 0) bsum[blockIdx.x] = sm[0];
}

// exclusive scan of nb (<=1024) block sums, in place. Shuffle-based:
// per-wave inclusive scan + 16-wave LDS fixup (2 barriers vs 20).
__global__ void k_bscan(int* __restrict__ bsum, int nb) {
  int i = threadIdx.x;
  int v = (i < nb) ? bsum[i] : 0;
  int x = v;
#pragma unroll
  for (int d = 1; d < 64; d <<= 1) {
    int t = __shfl_up(x, d);
    if ((i & 63) >= d) x += t;
  }
  __shared__ int wsum[16];
  if ((i & 63) == 63) wsum[i >> 6] = x;
  __syncthreads();
  if (i < 16) {
    int w = wsum[i];
    int y = w;
#pragma unroll
    for (int d = 1; d < 16; d <<= 1) {
      int t = __shfl_up(y, d, 16);
      if (i >= d) y += t;
    }
    wsum[i] = y - w;  // exclusive wave base
  }
  __syncthreads();
  if (i < nb) bsum[i] = (x - v) + wsum[i >> 6];
}

__global__ void k_ptr(const int* __restrict__ cnt, const int* __restrict__ bsum,
                      int* __restrict__ ptr, int* __restrict__ cursor, int M) {
  __shared__ int sm[256];
  int i = blockIdx.x * 256 + threadIdx.x;
  int v = (i < M) ? cnt[i] : 0;
  sm[threadIdx.x] = v;
  __syncthreads();
  for (int st = 1; st < 256; st <<= 1) {
    int t = (threadIdx.x >= st) ? sm[threadIdx.x - st] : 0;
    __syncthreads();
    sm[threadIdx.x] += t;
    __syncthreads();
  }
  if (i < M) {
    int e = bsum[blockIdx.x] + sm[threadIdx.x] - v;
    ptr[i] = e;
    cursor[i] = e;
  }
}

__global__ void k_scatter(const int* __restrict__ seg, int* __restrict__ cursor,
                          int* __restrict__ plist, int Npts) {
  int t = blockIdx.x * 256 + threadIdx.x;
  if (t < Npts) {
    int pos = atomicAdd(cursor + seg[t], 1);
    plist[pos] = t;
  }
}

// per (voxel, 4-channel group): mean of member point features -> bf16 vpad.
__global__ void k_gmean(const float* __restrict__ hid, const float* __restrict__ qry,
                        const int* __restrict__ ptr, const int* __restrict__ cnt,
                        const int* __restrict__ plist, bf16* __restrict__ vpad, int M) {
  int t = blockIdx.x * 256 + threadIdx.x;
  if (t >= (M + 1) * 48) return;
  int v = t / 48;
  int q = t - v * 48;
  f32x4 a = {0.f, 0.f, 0.f, 0.f};
  if (v < M) {
    int st = ptr[v], n = cnt[v];
    const float* base = (q < 24) ? (hid + q * 4) : (qry + (q - 24) * 4);
    for (int j = 0; j < n; j++) {
      int p = plist[st + j];
      a += *(const f32x4*)(base + (size_t)p * HIDC);
    }
    a *= (1.0f / (float)(n > 0 ? n : 1));
  }
  bf16x4 o;
#pragma unroll
  for (int j = 0; j < 4; j++) o[j] = (bf16)a[j];
  *(bf16x4*)(vpad + (size_t)v * CINC + q * 4) = o;
}

// ---------------------------------------------------------------------------
// K3: sparse conv. Round-0 loop (best measured structure), UNTOUCHED: 256 thr
// = 4 waves x 32 rows (rt=2), B double-buffered in LDS via register staging
// (breg) a full stage ahead; A-frags + nbr software-pipelined one stage
// ahead; one __syncthreads per stage. Epilogue reworked on counter evidence:
//  - barrier, then per-wave LDS transpose -> full-128B-line f32x4 stores
//    (r6 FETCH 120MB vs r4 66MB: plain 4B-stride-64B stores cost ~53MB RMW)
//  - BN column stats reduced across waves in LDS first -> 192 atomics/block
//    instead of 768 on 3 hot cache lines.
// ---------------------------------------------------------------------------
__launch_bounds__(256, 3)
__global__ void k_conv(const bf16* __restrict__ vpad, const int* __restrict__ nbr,
                       const bf16* __restrict__ wpack, float* __restrict__ accbuf,
                       float* __restrict__ bnsum, int M, int nblk, int nper) {
  const int bx = (int)(blockIdx.x & 7) * nper + (int)(blockIdx.x >> 3);
  if (bx >= nblk) return;
  __shared__ __align__(16) char smem[40960];  // loop: Bb[2][20480]; epi: reuse
  const int tid = threadIdx.x;
  const int wave = tid >> 6;
  const int lane = tid & 63;
  const int m = lane & 15;
  const int quad = lane >> 4;
  const int rb = bx * 128 + wave * 32;

  f32x4 acc[2][6];
#pragma unroll
  for (int rt = 0; rt < 2; rt++)
#pragma unroll
    for (int ct = 0; ct < 6; ct++) {
      f32x4 z = {0.f, 0.f, 0.f, 0.f};
      acc[rt][ct] = z;
    }

  const char* wb = (const char*)wpack;
  i32x4 breg[5];
#pragma unroll
  for (int i = 0; i < 5; i++)
    breg[i] = *(const i32x4*)(wb + (size_t)(tid + 256 * i) * 16);

  // prologue: gidx for offset 0, A-frags for stage 0 (half0 -> kc 0..2)
  int gidx[2], gidx2[2];
#pragma unroll
  for (int rt = 0; rt < 2; rt++) {
    int r = rb + rt * 16 + m;
    gidx[rt] = (r < M) ? nbr[(size_t)r * 27] : M;
  }
  bf16x8 afn[2][3];
#pragma unroll
  for (int kc2 = 0; kc2 < 3; kc2++)
#pragma unroll
    for (int rt = 0; rt < 2; rt++)
      afn[rt][kc2] = *(const bf16x8*)(vpad + (size_t)gidx[rt] * CINC + kc2 * 32 + quad * 8);

  for (int s = 0; s < 54; s++) {
    const int buf = s & 1;
    {
      char* bbw = smem + (size_t)buf * STG_B;
#pragma unroll
      for (int i = 0; i < 5; i++)
        *(i32x4*)(bbw + (size_t)(tid + 256 * i) * 16) = breg[i];
    }
    __syncthreads();
    if (s < 53) {
      const char* src = wb + (size_t)(s + 1) * STG_B;
#pragma unroll
      for (int i = 0; i < 5; i++)
        breg[i] = *(const i32x4*)(src + (size_t)(tid + 256 * i) * 16);
    }
    // take the prefetched A-frags for this stage
    bf16x8 afc[2][3];
#pragma unroll
    for (int kc2 = 0; kc2 < 3; kc2++)
#pragma unroll
      for (int rt = 0; rt < 2; rt++) afc[rt][kc2] = afn[rt][kc2];

    const int half = s & 1;
    const int off = s >> 1;
    if (half == 0) {
      // prefetch nbr for off+1 (used one stage later)
      const int offn = off + 1;
#pragma unroll
      for (int rt = 0; rt < 2; rt++) {
        int r = rb + rt * 16 + m;
        gidx2[rt] = (r < M && offn < 27) ? nbr[(size_t)r * 27 + offn] : M;
      }
      // prefetch A for stage s+1 (half1 of same off -> kc 3..5, rows gidx)
      if (s < 53) {
#pragma unroll
        for (int kc2 = 0; kc2 < 3; kc2++)
#pragma unroll
          for (int rt = 0; rt < 2; rt++)
            afn[rt][kc2] = *(const bf16x8*)(vpad + (size_t)gidx[rt] * CINC +
                                            (kc2 + 3) * 32 + quad * 8);
      }
    } else {
      // prefetch A for stage s+1 (half0 of off+1 -> kc 0..2, rows gidx2)
      if (s < 53) {
#pragma unroll
        for (int kc2 = 0; kc2 < 3; kc2++)
#pragma unroll
          for (int rt = 0; rt < 2; rt++)
            afn[rt][kc2] = *(const bf16x8*)(vpad + (size_t)gidx2[rt] * CINC +
                                            kc2 * 32 + quad * 8);
      }
      gidx[0] = gidx2[0];
      gidx[1] = gidx2[1];
    }

    const char* bbr = smem + (size_t)buf * STG_B;
#pragma unroll
    for (int kc2 = 0; kc2 < 3; kc2++) {
#pragma unroll
      for (int ct = 0; ct < 6; ct++) {
        bf16x8 bfm = *(const bf16x8*)(bbr + (size_t)(kc2 * 6 + ct) * 1024 + (size_t)lane * 16);
#pragma unroll
        for (int rt = 0; rt < 2; rt++)
          acc[rt][ct] = __builtin_amdgcn_mfma_f32_16x16x32_bf16(afc[rt][kc2], bfm, acc[rt][ct], 0, 0, 0);
      }
    }
  }

  // ---- epilogue ----
  __syncthreads();  // all waves done reading Bb before LDS is reused

  // BN partials (exact fp32, from registers). C frag: row quad*4+rr, col ct*16+m.
  float ps[6], pq[6];
#pragma unroll
  for (int ct = 0; ct < 6; ct++) { ps[ct] = 0.f; pq[ct] = 0.f; }
#pragma unroll
  for (int rt = 0; rt < 2; rt++)
#pragma unroll
    for (int rr = 0; rr < 4; rr++) {
      const int r2 = rb + rt * 16 + quad * 4 + rr;
      if (r2 < M) {
#pragma unroll
        for (int ct = 0; ct < 6; ct++) {
          float v = acc[rt][ct][rr];
          ps[ct] += v;
          pq[ct] += v * v;
        }
      }
    }
  // wave-partials into LDS (region beyond the transpose area)
  float* bnp = (float*)(smem + 32768);  // [4][192] sum, then reduce
  float* bnq = (float*)(smem + 32768 + 4 * 192 * 4 - 0) + 0;  // laid out below
#pragma unroll
  for (int ct = 0; ct < 6; ct++) {
    float s1 = ps[ct], s2 = pq[ct];
    s1 += __shfl_xor(s1, 16);
    s2 += __shfl_xor(s2, 16);
    s1 += __shfl_xor(s1, 32);
    s2 += __shfl_xor(s2, 32);
    if (quad == 0) {
      bnp[wave * 96 + ct * 16 + m] = s1;          // [4][96] at 32768
      bnp[384 + wave * 96 + ct * 16 + m] = s2;    // [4][96] at 32768+1536
    }
  }
  (void)bnq;

  // per-wave LDS transpose (same-wave ds ordering) -> full-line f32x4 stores
  float(*trw)[98] = (float(*)[98])(smem + wave * (16 * 98 * 4));
  const int erow = lane >> 3;       // 0..7
  const int ecb = (lane & 7) * 4;   // 0,4,..,28
#pragma unroll
  for (int rt = 0; rt < 2; rt++) {
#pragma unroll
    for (int ct = 0; ct < 6; ct++)
#pragma unroll
      for (int rr = 0; rr < 4; rr++)
        trw[quad * 4 + rr][ct * 16 + m] = acc[rt][ct][rr];
#pragma unroll
    for (int rh = 0; rh < 2; rh++) {
      const int row = rh * 8 + erow;
      const int r2 = rb + rt * 16 + row;
      if (r2 < M) {
#pragma unroll
        for (int it = 0; it < 3; it++) {
          f32x4 v = *(const f32x4*)&trw[row][it * 32 + ecb];
          *(f32x4*)(accbuf + (size_t)r2 * HIDC + it * 32 + ecb) = v;
        }
      }
    }
  }

  __syncthreads();  // bnp partials visible
  if (tid < 192) {  // 96 sums + 96 sumsqs, one atomic each (was 768/block)
    const int which = tid / 96;           // 0: sum, 1: sumsq
    const int c = tid - which * 96;
    const float* basep = bnp + which * 384;
    float s = basep[c] + basep[96 + c] + basep[192 + c] + basep[288 + c];
    atomicAdd(bnsum + which * 96 + c, s);
  }
}

// ---------------------------------------------------------------------------
// K5: y = relu(acc*scale + shift) -> bf16 ypad, zero pad row M. BN finalize
// folded in; vectorized x8 (f32x4 x2 -> bf16x8 per thread).
// ---------------------------------------------------------------------------
__global__ void k_bnapply(const float* __restrict__ accbuf, const float* __restrict__ bnsum,
                          const float* __restrict__ gamma, const float* __restrict__ beta,
                          bf16* __restrict__ ypad, int M) {
  __shared__ float ssc[96], ssh[96];
  if (threadIdx.x < 96) {
    int c = threadIdx.x;
    float inv = 1.0f / (float)M;
    float mu = bnsum[c] * inv;
    float var = fmaxf(bnsum[96 + c] * inv - mu * mu, 0.f);
    float sc = gamma[c] * rsqrtf(var + EPSC);
    ssc[c] = sc;
    ssh[c] = beta[c] - mu * sc;
  }
  __syncthreads();
  int t = blockIdx.x * 256 + threadIdx.x;
  if (t >= (M + 1) * 12) return;
  int v = t / 12;
  int g = t - v * 12;
  bf16x8 o;
  if (v < M) {
    f32x4 a = *(const f32x4*)(accbuf + (size_t)v * HIDC + g * 8);
    f32x4 b = *(const f32x4*)(accbuf + (size_t)v * HIDC + g * 8 + 4);
#pragma unroll
    for (int j = 0; j < 4; j++) {
      o[j] = (bf16)fmaxf(a[j] * ssc[g * 8 + j] + ssh[g * 8 + j], 0.f);
      o[4 + j] = (bf16)fmaxf(b[j] * ssc[g * 8 + 4 + j] + ssh[g * 8 + 4 + j], 0.f);
    }
  } else {
#pragma unroll
    for (int j = 0; j < 8; j++) o[j] = (bf16)0.f;
  }
  *(bf16x8*)(ypad + (size_t)v * HIDC + g * 8) = o;
}

// ---------------------------------------------------------------------------
// K6: lin = hx @ W_lin + b_lin (fp32 in, bf16 MFMA, bf16 out). LDS-free,
// 256 thr = 4 waves x 32 rows; B fragments direct from L2-resident wlpack
// (stage-padded layout: half = kc>=3).
// ---------------------------------------------------------------------------
__launch_bounds__(256, 4)
__global__ void k_linear(const float* __restrict__ hid, const float* __restrict__ qry,
                         const bf16* __restrict__ wlpack, const float* __restrict__ blin,
                         bf16* __restrict__ lin, int Npts) {
  const int tid = threadIdx.x;
  const int wave = tid >> 6;
  const int lane = tid & 63;
  const int m = lane & 15;
  const int quad = lane >> 4;
  const int rb = blockIdx.x * 128 + wave * 32;

  f32x4 acc[2][6];
#pragma unroll
  for (int rt = 0; rt < 2; rt++)
#pragma unroll
    for (int ct = 0; ct < 6; ct++) {
      f32x4 z = {0.f, 0.f, 0.f, 0.f};
      acc[rt][ct] = z;
    }

  int prow[2];
#pragma unroll
  for (int rt = 0; rt < 2; rt++) {
    int r = rb + rt * 16 + m;
    prow[rt] = (r < Npts) ? r : (Npts - 1);
  }
  const char* wp = (const char*)wlpack;
#pragma unroll
  for (int kc = 0; kc < 6; kc++) {
    const float* srcA = (kc < 3) ? (hid + kc * 32) : (qry + (kc - 3) * 32);
    bf16x8 af[2];
#pragma unroll
    for (int rt = 0; rt < 2; rt++) {
      const float* pA = srcA + (size_t)prow[rt] * HIDC + quad * 8;
      f32x4 lo = *(const f32x4*)pA;
      f32x4 hi = *(const f32x4*)(pA + 4);
#pragma unroll
      for (int j = 0; j < 4; j++) {
        af[rt][j] = (bf16)lo[j];
        af[rt][4 + j] = (bf16)hi[j];
      }
    }
    const int half = (kc >= 3) ? 1 : 0;
    const int kcl = kc - half * 3;
#pragma unroll
    for (int ct = 0; ct < 6; ct++) {
      bf16x8 bfm = *(const bf16x8*)(wp + (size_t)half * STG_B +
                                    (size_t)((kcl * 6 + ct) * 64 + lane) * 16);
#pragma unroll
      for (int rt = 0; rt < 2; rt++)
        acc[rt][ct] = __builtin_amdgcn_mfma_f32_16x16x32_bf16(af[rt], bfm, acc[rt][ct], 0, 0, 0);
    }
  }
  float bl[6];
#pragma unroll
  for (int ct = 0; ct < 6; ct++) bl[ct] = blin[ct * 16 + m];
#pragma unroll
  for (int rt = 0; rt < 2; rt++)
#pragma unroll
    for (int rr = 0; rr < 4; rr++) {
      const int r2 = rb + rt * 16 + quad * 4 + rr;
      if (r2 < Npts) {
        bf16* dst = lin + (size_t)r2 * HIDC + m;
#pragma unroll
        for (int ct = 0; ct < 6; ct++)
          dst[ct * 16] = (bf16)(acc[rt][ct][rr] + bl[ct]);
      }
    }
}

// ---------------------------------------------------------------------------
// K7: out = lin + sum_k w[p,k] * ypad[cidx[p,k]]  (8-channel groups)
// ---------------------------------------------------------------------------
__global__ void k_out(const bf16* __restrict__ lin, const bf16* __restrict__ ypad,
                      const float* __restrict__ cw, const int* __restrict__ cidx,
                      float* __restrict__ out, int Npts) {
  int t = blockIdx.x * 256 + threadIdx.x;
  if (t >= Npts * 12) return;
  int p = t / 12;
  int g = t - p * 12;
  float a[8];
  bf16x8 lv = *(const bf16x8*)(lin + (size_t)p * HIDC + g * 8);
#pragma unroll
  for (int j = 0; j < 8; j++) a[j] = (float)lv[j];
  f32x4 w0 = *(const f32x4*)(cw + (size_t)p * 8);
  f32x4 w1 = *(const f32x4*)(cw + (size_t)p * 8 + 4);
  const i32x4* cp = (const i32x4*)(cidx + (size_t)p * 8);
  i32x4 c0 = cp[0], c1 = cp[1];
#pragma unroll
  for (int k = 0; k < 8; k++) {
    int idx = (k < 4) ? c0[k] : c1[k - 4];
    float wk = (k < 4) ? w0[k] : w1[k - 4];
    bf16x8 yv = *(const bf16x8*)(ypad + (size_t)idx * HIDC + g * 8);
#pragma unroll
    for (int j = 0; j < 8; j++) a[j] += wk * (float)yv[j];
  }
  float* op = out + (size_t)p * HIDC + g * 8;
  f32x4 s0, s1;
#pragma unroll
  for (int j = 0; j < 4; j++) { s0[j] = a[j]; s1[j] = a[4 + j]; }
  *(f32x4*)op = s0;
  *(f32x4*)(op + 4) = s1;
}

// ---------------------------------------------------------------------------
extern "C" void kernel_launch(void* const* d_in, const int* in_sizes, int n_in,
                              void* d_out, int out_size, void* d_ws, size_t ws_size,
                              hipStream_t stream) {
  const float* hid = (const float*)d_in[0];
  const float* qry = (const float*)d_in[1];
  const float* Wc = (const float*)d_in[2];
  const float* gamma = (const float*)d_in[3];
  const float* beta = (const float*)d_in[4];
  const float* Wl = (const float*)d_in[5];
  const float* blin = (const float*)d_in[6];
  const float* cw = (const float*)d_in[7];
  const int* seg = (const int*)d_in[8];
  const int* nbr = (const int*)d_in[9];
  const int* cidx = (const int*)d_in[10];
  float* out = (float*)d_out;
  const int Npts = in_sizes[0] / HIDC;
  const int M = in_sizes[9] / 27;

  // ---- workspace layout ----
  // [cnt | bnsum]  <- single memset
  // region A: accbuf fp32 [M,96] (K3..K5) -> lin bf16 [N,96] (K6-K7) overlay
  // region B: vpad bf16 [M+1,192] (gmean..conv) -> ypad bf16 [M+1,96] overlay
  char* ws = (char*)d_ws;
  size_t cur = 0;
  auto alloc = [&](size_t b) { size_t o = cur; cur = (cur + b + 255) & ~(size_t)255; return o; };
  size_t o_cnt = alloc((size_t)M * 4);
  size_t o_bn = alloc(192 * 4);
  size_t zend = cur;  // memset range [0, zend): cnt + bnsum
  size_t o_ptr = alloc((size_t)M * 4);
  size_t o_cur = alloc((size_t)M * 4);
  size_t o_pl = alloc((size_t)Npts * 4);
  size_t o_bs = alloc(1024 * 4);
  size_t RA = (size_t)M * HIDC * 4;
  size_t needA = (size_t)Npts * HIDC * 2;
  if (needA > RA) RA = needA;
  size_t o_A = alloc(RA);
  size_t o_B = alloc((size_t)(M + 1) * CINC * 2);
  size_t o_wpack = alloc((size_t)56 * STG_B);
  (void)ws_size; (void)n_in; (void)out_size;

  int* cnt = (int*)(ws + o_cnt);
  float* bnsum = (float*)(ws + o_bn);
  int* ptr = (int*)(ws + o_ptr);
  int* cursor = (int*)(ws + o_cur);
  int* plist = (int*)(ws + o_pl);
  int* bsum = (int*)(ws + o_bs);
  float* accbuf = (float*)(ws + o_A);
  bf16* lin = (bf16*)(ws + o_A);
  bf16* vpad = (bf16*)(ws + o_B);
  bf16* ypad = (bf16*)(ws + o_B);
  bf16* wpack = (bf16*)(ws + o_wpack);
  bf16* wlpack = (bf16*)(ws + o_wpack + (size_t)54 * STG_B);

  // zero cnt + bnsum (adjacent at front; ws poisoned 0xAA each call)
  hipMemsetAsync(ws, 0, zend, stream);

  int totalRepack = 28 * 18432;
  k_repack<<<(totalRepack + 255) / 256, 256, 0, stream>>>(Wc, Wl, wpack, totalRepack);

  // voxelize: count -> scan -> scatter -> gather-mean
  int nb = (M + 255) / 256;
  k_count<<<(Npts + 255) / 256, 256, 0, stream>>>(seg, cnt, Npts);
  k_bsum<<<nb, 256, 0, stream>>>(cnt, bsum, M);
  k_bscan<<<1, 1024, 0, stream>>>(bsum, nb);
  k_ptr<<<nb, 256, 0, stream>>>(cnt, bsum, ptr, cursor, M);
  k_scatter<<<(Npts + 255) / 256, 256, 0, stream>>>(seg, cursor, plist, Npts);
  k_gmean<<<(((M + 1) * 48) + 255) / 256, 256, 0, stream>>>(hid, qry, ptr, cnt, plist, vpad, M);

  int nblk = (M + 127) / 128;
  int nper = (nblk + 7) / 8;
  k_conv<<<nper * 8, 256, 0, stream>>>(vpad, nbr, wpack, accbuf, bnsum, M, nblk, nper);
  k_bnapply<<<((M + 1) * 12 + 255) / 256, 256, 0, stream>>>(accbuf, bnsum, gamma, beta, ypad, M);
  k_linear<<<(Npts + 127) / 128, 256, 0, stream>>>(hid, qry, wlpack, blin, lin, Npts);
  k_out<<<(Npts * 12 + 255) / 256, 256, 0, stream>>>(lin, ypad, cw, cidx, out, Npts);
}

// Round 8
// 377.304 us; speedup vs baseline: 1.1279x; 1.0129x over previous
//
#include <hip/hip_runtime.h>
#include <hip/hip_bf16.h>
#include <cstdint>

typedef __bf16 bf16;
typedef __bf16 bf16x8 __attribute__((ext_vector_type(8)));
typedef __bf16 bf16x4 __attribute__((ext_vector_type(4)));
typedef float f32x4 __attribute__((ext_vector_type(4)));
typedef int i32x4 __attribute__((ext_vector_type(4)));

#define HIDC 96
#define CINC 192
#define EPSC 1e-5f

// wpack layout: 56 stages (28 offs x 2 halves) x 20480 B. Real payload per
// stage = 18 cix x 1024 B = 18432 B (+2048 B pad -> uniform 5x16B chunks per
// thread at 256 threads). cix = kc_local*6+ct, element =
//   W[off][k = (half*3+kc_local)*32 + (lane>>4)*8 + j][col = ct*16 + (lane&15)]
#define STG_B 20480
#define STG_ELEM 10240

// ---------------------------------------------------------------------------
// K0: repack W_conv [27][192][96] fp32 + W_lin [192][96] fp32 -> bf16 wpack.
// ---------------------------------------------------------------------------
__global__ void k_repack(const float* __restrict__ Wc, const float* __restrict__ Wl,
                         bf16* __restrict__ dst, int total) {
  int t = blockIdx.x * 256 + threadIdx.x;
  if (t >= total) return;              // total = 28*18432 real elements
  int off = t / 18432;
  int rem = t - off * 18432;
  int cix = rem >> 9;
  int lane = (rem >> 3) & 63;
  int j = rem & 7;
  int k = (cix / 6) * 32 + ((lane >> 4) << 3) + j;
  int col = (cix % 6) * 16 + (lane & 15);
  const float* src = (off < 27) ? (Wc + ((size_t)off * CINC + k) * HIDC + col)
                                : (Wl + (size_t)k * HIDC + col);
  int half = (cix >= 18) ? 1 : 0;
  size_t de = (size_t)(off * 2 + half) * STG_ELEM + (size_t)(rem - half * 9216);
  dst[de] = (bf16)(*src);
}

// ---------------------------------------------------------------------------
// Voxelize path: counting-sort + gather-mean (replaces 23M fp32 atomics).
// ---------------------------------------------------------------------------
__global__ void k_count(const int* __restrict__ seg, int* __restrict__ cnt, int Npts) {
  int t = blockIdx.x * 256 + threadIdx.x;
  if (t < Npts) atomicAdd(cnt + seg[t], 1);
}

__global__ void k_bsum(const int* __restrict__ cnt, int* __restrict__ bsum, int M) {
  __shared__ int sm[256];
  int i = blockIdx.x * 256 + threadIdx.x;
  sm[threadIdx.x] = (i < M) ? cnt[i] : 0;
  __syncthreads();
  for (int st = 128; st > 0; st >>= 1) {
    if (threadIdx.x < st) sm[threadIdx.x] += sm[threadIdx.x + st];
    __syncthreads();
  }
  if (threadIdx.x == 0) bsum[blockIdx.x] = sm[0];
}

// exclusive scan of nb (<=1024) block sums, in place. Shuffle-based:
// per-wave inclusive scan + 16-wave LDS fixup (2 barriers vs 20).
__global__ void k_bscan(int* __restrict__ bsum, int nb) {
  int i = threadIdx.x;
  int v = (i < nb) ? bsum[i] : 0;
  int x = v;
#pragma unroll
  for (int d = 1; d < 64; d <<= 1) {
    int t = __shfl_up(x, d);
    if ((i & 63) >= d) x += t;
  }
  __shared__ int wsum[16];
  if ((i & 63) == 63) wsum[i >> 6] = x;
  __syncthreads();
  if (i < 16) {
    int w = wsum[i];
    int y = w;
#pragma unroll
    for (int d = 1; d < 16; d <<= 1) {
      int t = __shfl_up(y, d, 16);
      if (i >= d) y += t;
    }
    wsum[i] = y - w;  // exclusive wave base
  }
  __syncthreads();
  if (i < nb) bsum[i] = (x - v) + wsum[i >> 6];
}

__global__ void k_ptr(const int* __restrict__ cnt, const int* __restrict__ bsum,
                      int* __restrict__ ptr, int* __restrict__ cursor, int M) {
  __shared__ int sm[256];
  int i = blockIdx.x * 256 + threadIdx.x;
  int v = (i < M) ? cnt[i] : 0;
  sm[threadIdx.x] = v;
  __syncthreads();
  for (int st = 1; st < 256; st <<= 1) {
    int t = (threadIdx.x >= st) ? sm[threadIdx.x - st] : 0;
    __syncthreads();
    sm[threadIdx.x] += t;
    __syncthreads();
  }
  if (i < M) {
    int e = bsum[blockIdx.x] + sm[threadIdx.x] - v;
    ptr[i] = e;
    cursor[i] = e;
  }
}

__global__ void k_scatter(const int* __restrict__ seg, int* __restrict__ cursor,
                          int* __restrict__ plist, int Npts) {
  int t = blockIdx.x * 256 + threadIdx.x;
  if (t < Npts) {
    int pos = atomicAdd(cursor + seg[t], 1);
    plist[pos] = t;
  }
}

// per (voxel, 4-channel group): mean of member point features -> bf16 vpad.
__global__ void k_gmean(const float* __restrict__ hid, const float* __restrict__ qry,
                        const int* __restrict__ ptr, const int* __restrict__ cnt,
                        const int* __restrict__ plist, bf16* __restrict__ vpad, int M) {
  int t = blockIdx.x * 256 + threadIdx.x;
  if (t >= (M + 1) * 48) return;
  int v = t / 48;
  int q = t - v * 48;
  f32x4 a = {0.f, 0.f, 0.f, 0.f};
  if (v < M) {
    int st = ptr[v], n = cnt[v];
    const float* base = (q < 24) ? (hid + q * 4) : (qry + (q - 24) * 4);
    for (int j = 0; j < n; j++) {
      int p = plist[st + j];
      a += *(const f32x4*)(base + (size_t)p * HIDC);
    }
    a *= (1.0f / (float)(n > 0 ? n : 1));
  }
  bf16x4 o;
#pragma unroll
  for (int j = 0; j < 4; j++) o[j] = (bf16)a[j];
  *(bf16x4*)(vpad + (size_t)v * CINC + q * 4) = o;
}

// ---------------------------------------------------------------------------
// K3: sparse conv. Round-0 loop (best measured structure, clock-normalized
// across 7 rounds), UNTOUCHED: 256 thr = 4 waves x 32 rows (rt=2), B
// double-buffered in LDS via register staging (breg) a full stage ahead;
// A-frags + nbr software-pipelined one stage ahead; one __syncthreads per
// stage. Epilogue: LDS-transpose full-line stores + cross-wave-reduced BN
// stats (192 atomics/block).
// ---------------------------------------------------------------------------
__launch_bounds__(256, 3)
__global__ void k_conv(const bf16* __restrict__ vpad, const int* __restrict__ nbr,
                       const bf16* __restrict__ wpack, float* __restrict__ accbuf,
                       float* __restrict__ bnsum, int M, int nblk, int nper) {
  const int bx = (int)(blockIdx.x & 7) * nper + (int)(blockIdx.x >> 3);
  if (bx >= nblk) return;
  __shared__ __align__(16) char smem[40960];  // loop: Bb[2][20480]; epi: reuse
  const int tid = threadIdx.x;
  const int wave = tid >> 6;
  const int lane = tid & 63;
  const int m = lane & 15;
  const int quad = lane >> 4;
  const int rb = bx * 128 + wave * 32;

  f32x4 acc[2][6];
#pragma unroll
  for (int rt = 0; rt < 2; rt++)
#pragma unroll
    for (int ct = 0; ct < 6; ct++) {
      f32x4 z = {0.f, 0.f, 0.f, 0.f};
      acc[rt][ct] = z;
    }

  const char* wb = (const char*)wpack;
  i32x4 breg[5];
#pragma unroll
  for (int i = 0; i < 5; i++)
    breg[i] = *(const i32x4*)(wb + (size_t)(tid + 256 * i) * 16);

  // prologue: gidx for offset 0, A-frags for stage 0 (half0 -> kc 0..2)
  int gidx[2], gidx2[2];
#pragma unroll
  for (int rt = 0; rt < 2; rt++) {
    int r = rb + rt * 16 + m;
    gidx[rt] = (r < M) ? nbr[(size_t)r * 27] : M;
  }
  bf16x8 afn[2][3];
#pragma unroll
  for (int kc2 = 0; kc2 < 3; kc2++)
#pragma unroll
    for (int rt = 0; rt < 2; rt++)
      afn[rt][kc2] = *(const bf16x8*)(vpad + (size_t)gidx[rt] * CINC + kc2 * 32 + quad * 8);

  for (int s = 0; s < 54; s++) {
    const int buf = s & 1;
    {
      char* bbw = smem + (size_t)buf * STG_B;
#pragma unroll
      for (int i = 0; i < 5; i++)
        *(i32x4*)(bbw + (size_t)(tid + 256 * i) * 16) = breg[i];
    }
    __syncthreads();
    if (s < 53) {
      const char* src = wb + (size_t)(s + 1) * STG_B;
#pragma unroll
      for (int i = 0; i < 5; i++)
        breg[i] = *(const i32x4*)(src + (size_t)(tid + 256 * i) * 16);
    }
    // take the prefetched A-frags for this stage
    bf16x8 afc[2][3];
#pragma unroll
    for (int kc2 = 0; kc2 < 3; kc2++)
#pragma unroll
      for (int rt = 0; rt < 2; rt++) afc[rt][kc2] = afn[rt][kc2];

    const int half = s & 1;
    const int off = s >> 1;
    if (half == 0) {
      // prefetch nbr for off+1 (used one stage later)
      const int offn = off + 1;
#pragma unroll
      for (int rt = 0; rt < 2; rt++) {
        int r = rb + rt * 16 + m;
        gidx2[rt] = (r < M && offn < 27) ? nbr[(size_t)r * 27 + offn] : M;
      }
      // prefetch A for stage s+1 (half1 of same off -> kc 3..5, rows gidx)
      if (s < 53) {
#pragma unroll
        for (int kc2 = 0; kc2 < 3; kc2++)
#pragma unroll
          for (int rt = 0; rt < 2; rt++)
            afn[rt][kc2] = *(const bf16x8*)(vpad + (size_t)gidx[rt] * CINC +
                                            (kc2 + 3) * 32 + quad * 8);
      }
    } else {
      // prefetch A for stage s+1 (half0 of off+1 -> kc 0..2, rows gidx2)
      if (s < 53) {
#pragma unroll
        for (int kc2 = 0; kc2 < 3; kc2++)
#pragma unroll
          for (int rt = 0; rt < 2; rt++)
            afn[rt][kc2] = *(const bf16x8*)(vpad + (size_t)gidx2[rt] * CINC +
                                            kc2 * 32 + quad * 8);
      }
      gidx[0] = gidx2[0];
      gidx[1] = gidx2[1];
    }

    const char* bbr = smem + (size_t)buf * STG_B;
#pragma unroll
    for (int kc2 = 0; kc2 < 3; kc2++) {
#pragma unroll
      for (int ct = 0; ct < 6; ct++) {
        bf16x8 bfm = *(const bf16x8*)(bbr + (size_t)(kc2 * 6 + ct) * 1024 + (size_t)lane * 16);
#pragma unroll
        for (int rt = 0; rt < 2; rt++)
          acc[rt][ct] = __builtin_amdgcn_mfma_f32_16x16x32_bf16(afc[rt][kc2], bfm, acc[rt][ct], 0, 0, 0);
      }
    }
  }

  // ---- epilogue ----
  __syncthreads();  // all waves done reading Bb before LDS is reused

  // BN partials (exact fp32, from registers). C frag: row quad*4+rr, col ct*16+m.
  float ps[6], pq[6];
#pragma unroll
  for (int ct = 0; ct < 6; ct++) { ps[ct] = 0.f; pq[ct] = 0.f; }
#pragma unroll
  for (int rt = 0; rt < 2; rt++)
#pragma unroll
    for (int rr = 0; rr < 4; rr++) {
      const int r2 = rb + rt * 16 + quad * 4 + rr;
      if (r2 < M) {
#pragma unroll
        for (int ct = 0; ct < 6; ct++) {
          float v = acc[rt][ct][rr];
          ps[ct] += v;
          pq[ct] += v * v;
        }
      }
    }
  float* bnp = (float*)(smem + 32768);  // [2][4][96] wave partials
#pragma unroll
  for (int ct = 0; ct < 6; ct++) {
    float s1 = ps[ct], s2 = pq[ct];
    s1 += __shfl_xor(s1, 16);
    s2 += __shfl_xor(s2, 16);
    s1 += __shfl_xor(s1, 32);
    s2 += __shfl_xor(s2, 32);
    if (quad == 0) {
      bnp[wave * 96 + ct * 16 + m] = s1;
      bnp[384 + wave * 96 + ct * 16 + m] = s2;
    }
  }

  // per-wave LDS transpose (same-wave ds ordering) -> full-line f32x4 stores
  float(*trw)[98] = (float(*)[98])(smem + wave * (16 * 98 * 4));
  const int erow = lane >> 3;       // 0..7
  const int ecb = (lane & 7) * 4;   // 0,4,..,28
#pragma unroll
  for (int rt = 0; rt < 2; rt++) {
#pragma unroll
    for (int ct = 0; ct < 6; ct++)
#pragma unroll
      for (int rr = 0; rr < 4; rr++)
        trw[quad * 4 + rr][ct * 16 + m] = acc[rt][ct][rr];
#pragma unroll
    for (int rh = 0; rh < 2; rh++) {
      const int row = rh * 8 + erow;
      const int r2 = rb + rt * 16 + row;
      if (r2 < M) {
#pragma unroll
        for (int it = 0; it < 3; it++) {
          f32x4 v = *(const f32x4*)&trw[row][it * 32 + ecb];
          *(f32x4*)(accbuf + (size_t)r2 * HIDC + it * 32 + ecb) = v;
        }
      }
    }
  }

  __syncthreads();  // bnp partials visible
  if (tid < 192) {  // 96 sums + 96 sumsqs, one atomic each
    const int which = tid / 96;           // 0: sum, 1: sumsq
    const int c = tid - which * 96;
    const float* basep = bnp + which * 384;
    float s = basep[c] + basep[96 + c] + basep[192 + c] + basep[288 + c];
    atomicAdd(bnsum + which * 96 + c, s);
  }
}

// ---------------------------------------------------------------------------
// K6: fused linear + devoxelize + residual:
//   phase 1: lin = hx @ W_lin + b_lin via MFMA (as before) -> LDS tile
//            (128 rows x 96 bf16; kills the 46MB lin global round-trip)
//   phase 2: out[p] = lin[p] + sum_k w[p,k] * relu(bn(accbuf[cidx[p,k]]))
//            BN scale/shift finalized per block into LDS from raw bnsum
//            (kills the 55MB k_bnapply pass entirely; fp32 gather is also
//            closer to the fp32 reference than the old bf16 ypad).
// ---------------------------------------------------------------------------
__launch_bounds__(256, 4)
__global__ void k_linout(const float* __restrict__ hid, const float* __restrict__ qry,
                         const bf16* __restrict__ wlpack, const float* __restrict__ blin,
                         const float* __restrict__ accbuf, const float* __restrict__ bnsum,
                         const float* __restrict__ gamma, const float* __restrict__ beta,
                         const float* __restrict__ cw, const int* __restrict__ cidx,
                         float* __restrict__ out, int Npts, int M) {
  __shared__ __align__(16) bf16 linT[128][HIDC];
  __shared__ float ssc[96], ssh[96];
  const int tid = threadIdx.x;
  // BN finalize (cheap, per block)
  if (tid < 96) {
    int c = tid;
    float inv = 1.0f / (float)M;
    float mu = bnsum[c] * inv;
    float var = fmaxf(bnsum[96 + c] * inv - mu * mu, 0.f);
    float sc = gamma[c] * rsqrtf(var + EPSC);
    ssc[c] = sc;
    ssh[c] = beta[c] - mu * sc;
  }

  // ---- phase 1: MFMA linear into LDS tile ----
  const int wave = tid >> 6;
  const int lane = tid & 63;
  const int m = lane & 15;
  const int quad = lane >> 4;
  const int rb = blockIdx.x * 128 + wave * 32;

  f32x4 acc[2][6];
#pragma unroll
  for (int rt = 0; rt < 2; rt++)
#pragma unroll
    for (int ct = 0; ct < 6; ct++) {
      f32x4 z = {0.f, 0.f, 0.f, 0.f};
      acc[rt][ct] = z;
    }

  int prow[2];
#pragma unroll
  for (int rt = 0; rt < 2; rt++) {
    int r = rb + rt * 16 + m;
    prow[rt] = (r < Npts) ? r : (Npts - 1);
  }
  const char* wp = (const char*)wlpack;
#pragma unroll
  for (int kc = 0; kc < 6; kc++) {
    const float* srcA = (kc < 3) ? (hid + kc * 32) : (qry + (kc - 3) * 32);
    bf16x8 af[2];
#pragma unroll
    for (int rt = 0; rt < 2; rt++) {
      const float* pA = srcA + (size_t)prow[rt] * HIDC + quad * 8;
      f32x4 lo = *(const f32x4*)pA;
      f32x4 hi = *(const f32x4*)(pA + 4);
#pragma unroll
      for (int j = 0; j < 4; j++) {
        af[rt][j] = (bf16)lo[j];
        af[rt][4 + j] = (bf16)hi[j];
      }
    }
    const int half = (kc >= 3) ? 1 : 0;
    const int kcl = kc - half * 3;
#pragma unroll
    for (int ct = 0; ct < 6; ct++) {
      bf16x8 bfm = *(const bf16x8*)(wp + (size_t)half * STG_B +
                                    (size_t)((kcl * 6 + ct) * 64 + lane) * 16);
#pragma unroll
      for (int rt = 0; rt < 2; rt++)
        acc[rt][ct] = __builtin_amdgcn_mfma_f32_16x16x32_bf16(af[rt], bfm, acc[rt][ct], 0, 0, 0);
    }
  }
  float bl[6];
#pragma unroll
  for (int ct = 0; ct < 6; ct++) bl[ct] = blin[ct * 16 + m];
  // store fragments to LDS tile (local row = wave*32 + rt*16 + quad*4 + rr)
#pragma unroll
  for (int rt = 0; rt < 2; rt++)
#pragma unroll
    for (int rr = 0; rr < 4; rr++) {
      const int lr = wave * 32 + rt * 16 + quad * 4 + rr;
#pragma unroll
      for (int ct = 0; ct < 6; ct++)
        linT[lr][ct * 16 + m] = (bf16)(acc[rt][ct][rr] + bl[ct]);
    }
  __syncthreads();

  // ---- phase 2: per (point, 8-ch group) gather-add, write out ----
  const int pbase = blockIdx.x * 128;
#pragma unroll
  for (int it = 0; it < 6; it++) {
    int task = it * 256 + tid;          // 128*12 = 1536 tasks
    int lp = task / 12;
    int g = task - lp * 12;
    int p = pbase + lp;
    if (p < Npts) {
      float a[8];
      bf16x8 lv = *(const bf16x8*)&linT[lp][g * 8];
#pragma unroll
      for (int j = 0; j < 8; j++) a[j] = (float)lv[j];
      f32x4 w0 = *(const f32x4*)(cw + (size_t)p * 8);
      f32x4 w1 = *(const f32x4*)(cw + (size_t)p * 8 + 4);
      const i32x4* cp = (const i32x4*)(cidx + (size_t)p * 8);
      i32x4 c0 = cp[0], c1 = cp[1];
#pragma unroll
      for (int k = 0; k < 8; k++) {
        int idx = (k < 4) ? c0[k] : c1[k - 4];
        float wk = (k < 4) ? w0[k] : w1[k - 4];
        const float* base = accbuf + (size_t)idx * HIDC + g * 8;
        f32x4 v0 = *(const f32x4*)base;
        f32x4 v1 = *(const f32x4*)(base + 4);
#pragma unroll
        for (int j = 0; j < 4; j++) {
          a[j] += wk * fmaxf(v0[j] * ssc[g * 8 + j] + ssh[g * 8 + j], 0.f);
          a[4 + j] += wk * fmaxf(v1[j] * ssc[g * 8 + 4 + j] + ssh[g * 8 + 4 + j], 0.f);
        }
      }
      float* op = out + (size_t)p * HIDC + g * 8;
      f32x4 s0, s1;
#pragma unroll
      for (int j = 0; j < 4; j++) { s0[j] = a[j]; s1[j] = a[4 + j]; }
      *(f32x4*)op = s0;
      *(f32x4*)(op + 4) = s1;
    }
  }
}

// ---------------------------------------------------------------------------
extern "C" void kernel_launch(void* const* d_in, const int* in_sizes, int n_in,
                              void* d_out, int out_size, void* d_ws, size_t ws_size,
                              hipStream_t stream) {
  const float* hid = (const float*)d_in[0];
  const float* qry = (const float*)d_in[1];
  const float* Wc = (const float*)d_in[2];
  const float* gamma = (const float*)d_in[3];
  const float* beta = (const float*)d_in[4];
  const float* Wl = (const float*)d_in[5];
  const float* blin = (const float*)d_in[6];
  const float* cw = (const float*)d_in[7];
  const int* seg = (const int*)d_in[8];
  const int* nbr = (const int*)d_in[9];
  const int* cidx = (const int*)d_in[10];
  float* out = (float*)d_out;
  const int Npts = in_sizes[0] / HIDC;
  const int M = in_sizes[9] / 27;

  // ---- workspace layout ----
  // [cnt | bnsum]  <- single memset
  // region A: accbuf fp32 [M+1,96] (K3..linout; row M = safe pad for w=0)
  // region B: vpad bf16 [M+1,192]
  char* ws = (char*)d_ws;
  size_t cur = 0;
  auto alloc = [&](size_t b) { size_t o = cur; cur = (cur + b + 255) & ~(size_t)255; return o; };
  size_t o_cnt = alloc((size_t)M * 4);
  size_t o_bn = alloc(192 * 4);
  size_t zend = cur;  // memset range [0, zend): cnt + bnsum
  size_t o_ptr = alloc((size_t)M * 4);
  size_t o_cur = alloc((size_t)M * 4);
  size_t o_pl = alloc((size_t)Npts * 4);
  size_t o_bs = alloc(1024 * 4);
  size_t o_A = alloc((size_t)(M + 1) * HIDC * 4);
  size_t o_B = alloc((size_t)(M + 1) * CINC * 2);
  size_t o_wpack = alloc((size_t)56 * STG_B);
  (void)ws_size; (void)n_in; (void)out_size;

  int* cnt = (int*)(ws + o_cnt);
  float* bnsum = (float*)(ws + o_bn);
  int* ptr = (int*)(ws + o_ptr);
  int* cursor = (int*)(ws + o_cur);
  int* plist = (int*)(ws + o_pl);
  int* bsum = (int*)(ws + o_bs);
  float* accbuf = (float*)(ws + o_A);
  bf16* vpad = (bf16*)(ws + o_B);
  bf16* wpack = (bf16*)(ws + o_wpack);
  bf16* wlpack = (bf16*)(ws + o_wpack + (size_t)54 * STG_B);

  // zero cnt + bnsum (adjacent at front; ws poisoned 0xAA each call)
  hipMemsetAsync(ws, 0, zend, stream);

  int totalRepack = 28 * 18432;
  k_repack<<<(totalRepack + 255) / 256, 256, 0, stream>>>(Wc, Wl, wpack, totalRepack);

  // voxelize: count -> scan -> scatter -> gather-mean
  int nb = (M + 255) / 256;
  k_count<<<(Npts + 255) / 256, 256, 0, stream>>>(seg, cnt, Npts);
  k_bsum<<<nb, 256, 0, stream>>>(cnt, bsum, M);
  k_bscan<<<1, 1024, 0, stream>>>(bsum, nb);
  k_ptr<<<nb, 256, 0, stream>>>(cnt, bsum, ptr, cursor, M);
  k_scatter<<<(Npts + 255) / 256, 256, 0, stream>>>(seg, cursor, plist, Npts);
  k_gmean<<<(((M + 1) * 48) + 255) / 256, 256, 0, stream>>>(hid, qry, ptr, cnt, plist, vpad, M);

  int nblk = (M + 127) / 128;
  int nper = (nblk + 7) / 8;
  k_conv<<<nper * 8, 256, 0, stream>>>(vpad, nbr, wpack, accbuf, bnsum, M, nblk, nper);
  k_linout<<<(Npts + 127) / 128, 256, 0, stream>>>(hid, qry, wlpack, blin, accbuf, bnsum,
                                                   gamma, beta, cw, cidx, out, Npts, M);
}

// Round 9
// 350.155 us; speedup vs baseline: 1.2153x; 1.0775x over previous
//
#include <hip/hip_runtime.h>
#include <hip/hip_bf16.h>
#include <cstdint>

typedef __bf16 bf16;
typedef __bf16 bf16x8 __attribute__((ext_vector_type(8)));
typedef __bf16 bf16x4 __attribute__((ext_vector_type(4)));
typedef float f32x4 __attribute__((ext_vector_type(4)));
typedef int i32x4 __attribute__((ext_vector_type(4)));

#define HIDC 96
#define CINC 192
#define EPSC 1e-5f

// wpack layout: 56 stages (28 offs x 2 halves) x 20480 B. Real payload per
// stage = 18 cix x 1024 B = 18432 B (+2048 B pad -> uniform 5x16B chunks per
// thread at 256 threads). cix = kc_local*6+ct, element =
//   W[off][k = (half*3+kc_local)*32 + (lane>>4)*8 + j][col = ct*16 + (lane&15)]
#define STG_B 20480
#define STG_ELEM 10240

// ---------------------------------------------------------------------------
// K0: repack W_conv [27][192][96] fp32 + W_lin [192][96] fp32 -> bf16 wpack.
// ---------------------------------------------------------------------------
__global__ void k_repack(const float* __restrict__ Wc, const float* __restrict__ Wl,
                         bf16* __restrict__ dst, int total) {
  int t = blockIdx.x * 256 + threadIdx.x;
  if (t >= total) return;              // total = 28*18432 real elements
  int off = t / 18432;
  int rem = t - off * 18432;
  int cix = rem >> 9;
  int lane = (rem >> 3) & 63;
  int j = rem & 7;
  int k = (cix / 6) * 32 + ((lane >> 4) << 3) + j;
  int col = (cix % 6) * 16 + (lane & 15);
  const float* src = (off < 27) ? (Wc + ((size_t)off * CINC + k) * HIDC + col)
                                : (Wl + (size_t)k * HIDC + col);
  int half = (cix >= 18) ? 1 : 0;
  size_t de = (size_t)(off * 2 + half) * STG_ELEM + (size_t)(rem - half * 9216);
  dst[de] = (bf16)(*src);
}

// ---------------------------------------------------------------------------
// Voxelize path: counting-sort + gather-mean (replaces 23M fp32 atomics).
// ---------------------------------------------------------------------------
__global__ void k_count(const int* __restrict__ seg, int* __restrict__ cnt, int Npts) {
  int t = blockIdx.x * 256 + threadIdx.x;
  if (t < Npts) atomicAdd(cnt + seg[t], 1);
}

__global__ void k_bsum(const int* __restrict__ cnt, int* __restrict__ bsum, int M) {
  __shared__ int sm[256];
  int i = blockIdx.x * 256 + threadIdx.x;
  sm[threadIdx.x] = (i < M) ? cnt[i] : 0;
  __syncthreads();
  for (int st = 128; st > 0; st >>= 1) {
    if (threadIdx.x < st) sm[threadIdx.x] += sm[threadIdx.x + st];
    __syncthreads();
  }
  if (threadIdx.x == 0) bsum[blockIdx.x] = sm[0];
}

// exclusive scan of nb (<=1024) block sums, in place. Shuffle-based:
// per-wave inclusive scan + 16-wave LDS fixup (2 barriers vs 20).
__global__ void k_bscan(int* __restrict__ bsum, int nb) {
  int i = threadIdx.x;
  int v = (i < nb) ? bsum[i] : 0;
  int x = v;
#pragma unroll
  for (int d = 1; d < 64; d <<= 1) {
    int t = __shfl_up(x, d);
    if ((i & 63) >= d) x += t;
  }
  __shared__ int wsum[16];
  if ((i & 63) == 63) wsum[i >> 6] = x;
  __syncthreads();
  if (i < 16) {
    int w = wsum[i];
    int y = w;
#pragma unroll
    for (int d = 1; d < 16; d <<= 1) {
      int t = __shfl_up(y, d, 16);
      if (i >= d) y += t;
    }
    wsum[i] = y - w;  // exclusive wave base
  }
  __syncthreads();
  if (i < nb) bsum[i] = (x - v) + wsum[i >> 6];
}

__global__ void k_ptr(const int* __restrict__ cnt, const int* __restrict__ bsum,
                      int* __restrict__ ptr, int* __restrict__ cursor, int M) {
  __shared__ int sm[256];
  int i = blockIdx.x * 256 + threadIdx.x;
  int v = (i < M) ? cnt[i] : 0;
  sm[threadIdx.x] = v;
  __syncthreads();
  for (int st = 1; st < 256; st <<= 1) {
    int t = (threadIdx.x >= st) ? sm[threadIdx.x - st] : 0;
    __syncthreads();
    sm[threadIdx.x] += t;
    __syncthreads();
  }
  if (i < M) {
    int e = bsum[blockIdx.x] + sm[threadIdx.x] - v;
    ptr[i] = e;
    cursor[i] = e;
  }
}

__global__ void k_scatter(const int* __restrict__ seg, int* __restrict__ cursor,
                          int* __restrict__ plist, int Npts) {
  int t = blockIdx.x * 256 + threadIdx.x;
  if (t < Npts) {
    int pos = atomicAdd(cursor + seg[t], 1);
    plist[pos] = t;
  }
}

// per (voxel, 8-channel group): mean of member point features -> bf16 vpad.
// 24 tasks/voxel (was 48): halves plist re-reads, 32B gathers per member.
__global__ void k_gmean(const float* __restrict__ hid, const float* __restrict__ qry,
                        const int* __restrict__ ptr, const int* __restrict__ cnt,
                        const int* __restrict__ plist, bf16* __restrict__ vpad, int M) {
  int t = blockIdx.x * 256 + threadIdx.x;
  if (t >= (M + 1) * 24) return;
  int v = t / 24;
  int q = t - v * 24;
  f32x4 a0 = {0.f, 0.f, 0.f, 0.f};
  f32x4 a1 = {0.f, 0.f, 0.f, 0.f};
  if (v < M) {
    int st = ptr[v], n = cnt[v];
    const float* base = (q < 12) ? (hid + q * 8) : (qry + (q - 12) * 8);
    for (int j = 0; j < n; j++) {
      int p = plist[st + j];
      a0 += *(const f32x4*)(base + (size_t)p * HIDC);
      a1 += *(const f32x4*)(base + (size_t)p * HIDC + 4);
    }
    float inv = 1.0f / (float)(n > 0 ? n : 1);
    a0 *= inv;
    a1 *= inv;
  }
  bf16x8 o;
#pragma unroll
  for (int j = 0; j < 4; j++) {
    o[j] = (bf16)a0[j];
    o[4 + j] = (bf16)a1[j];
  }
  *(bf16x8*)(vpad + (size_t)v * CINC + q * 8) = o;
}

// ---------------------------------------------------------------------------
// K3: sparse conv. Round-0 loop (best measured structure, clock-normalized
// across 8 rounds), UNTOUCHED: 256 thr = 4 waves x 32 rows (rt=2), B
// double-buffered in LDS via register staging (breg) a full stage ahead;
// A-frags + nbr software-pipelined one stage ahead; one __syncthreads per
// stage. Epilogue: BN stats exact in fp32 from registers (cross-wave LDS
// reduce, 192 atomics/block); acc materialized as BF16 (halves WRITE and
// halves the trilinear gather bytes in k_linout; BN is applied later from
// the fp32 stats so only the gather payload is quantized).
// ---------------------------------------------------------------------------
__launch_bounds__(256, 3)
__global__ void k_conv(const bf16* __restrict__ vpad, const int* __restrict__ nbr,
                       const bf16* __restrict__ wpack, bf16* __restrict__ accb,
                       float* __restrict__ bnsum, int M, int nblk, int nper) {
  const int bx = (int)(blockIdx.x & 7) * nper + (int)(blockIdx.x >> 3);
  if (bx >= nblk) return;
  __shared__ __align__(16) char smem[40960];  // loop: Bb[2][20480]; epi: reuse
  const int tid = threadIdx.x;
  const int wave = tid >> 6;
  const int lane = tid & 63;
  const int m = lane & 15;
  const int quad = lane >> 4;
  const int rb = bx * 128 + wave * 32;

  f32x4 acc[2][6];
#pragma unroll
  for (int rt = 0; rt < 2; rt++)
#pragma unroll
    for (int ct = 0; ct < 6; ct++) {
      f32x4 z = {0.f, 0.f, 0.f, 0.f};
      acc[rt][ct] = z;
    }

  const char* wb = (const char*)wpack;
  i32x4 breg[5];
#pragma unroll
  for (int i = 0; i < 5; i++)
    breg[i] = *(const i32x4*)(wb + (size_t)(tid + 256 * i) * 16);

  // prologue: gidx for offset 0, A-frags for stage 0 (half0 -> kc 0..2)
  int gidx[2], gidx2[2];
#pragma unroll
  for (int rt = 0; rt < 2; rt++) {
    int r = rb + rt * 16 + m;
    gidx[rt] = (r < M) ? nbr[(size_t)r * 27] : M;
  }
  bf16x8 afn[2][3];
#pragma unroll
  for (int kc2 = 0; kc2 < 3; kc2++)
#pragma unroll
    for (int rt = 0; rt < 2; rt++)
      afn[rt][kc2] = *(const bf16x8*)(vpad + (size_t)gidx[rt] * CINC + kc2 * 32 + quad * 8);

  for (int s = 0; s < 54; s++) {
    const int buf = s & 1;
    {
      char* bbw = smem + (size_t)buf * STG_B;
#pragma unroll
      for (int i = 0; i < 5; i++)
        *(i32x4*)(bbw + (size_t)(tid + 256 * i) * 16) = breg[i];
    }
    __syncthreads();
    if (s < 53) {
      const char* src = wb + (size_t)(s + 1) * STG_B;
#pragma unroll
      for (int i = 0; i < 5; i++)
        breg[i] = *(const i32x4*)(src + (size_t)(tid + 256 * i) * 16);
    }
    // take the prefetched A-frags for this stage
    bf16x8 afc[2][3];
#pragma unroll
    for (int kc2 = 0; kc2 < 3; kc2++)
#pragma unroll
      for (int rt = 0; rt < 2; rt++) afc[rt][kc2] = afn[rt][kc2];

    const int half = s & 1;
    const int off = s >> 1;
    if (half == 0) {
      // prefetch nbr for off+1 (used one stage later)
      const int offn = off + 1;
#pragma unroll
      for (int rt = 0; rt < 2; rt++) {
        int r = rb + rt * 16 + m;
        gidx2[rt] = (r < M && offn < 27) ? nbr[(size_t)r * 27 + offn] : M;
      }
      // prefetch A for stage s+1 (half1 of same off -> kc 3..5, rows gidx)
      if (s < 53) {
#pragma unroll
        for (int kc2 = 0; kc2 < 3; kc2++)
#pragma unroll
          for (int rt = 0; rt < 2; rt++)
            afn[rt][kc2] = *(const bf16x8*)(vpad + (size_t)gidx[rt] * CINC +
                                            (kc2 + 3) * 32 + quad * 8);
      }
    } else {
      // prefetch A for stage s+1 (half0 of off+1 -> kc 0..2, rows gidx2)
      if (s < 53) {
#pragma unroll
        for (int kc2 = 0; kc2 < 3; kc2++)
#pragma unroll
          for (int rt = 0; rt < 2; rt++)
            afn[rt][kc2] = *(const bf16x8*)(vpad + (size_t)gidx2[rt] * CINC +
                                            kc2 * 32 + quad * 8);
      }
      gidx[0] = gidx2[0];
      gidx[1] = gidx2[1];
    }

    const char* bbr = smem + (size_t)buf * STG_B;
#pragma unroll
    for (int kc2 = 0; kc2 < 3; kc2++) {
#pragma unroll
      for (int ct = 0; ct < 6; ct++) {
        bf16x8 bfm = *(const bf16x8*)(bbr + (size_t)(kc2 * 6 + ct) * 1024 + (size_t)lane * 16);
#pragma unroll
        for (int rt = 0; rt < 2; rt++)
          acc[rt][ct] = __builtin_amdgcn_mfma_f32_16x16x32_bf16(afc[rt][kc2], bfm, acc[rt][ct], 0, 0, 0);
      }
    }
  }

  // ---- epilogue ----
  __syncthreads();  // all waves done reading Bb before LDS is reused

  // BN partials (exact fp32, from registers). C frag: row quad*4+rr, col ct*16+m.
  float ps[6], pq[6];
#pragma unroll
  for (int ct = 0; ct < 6; ct++) { ps[ct] = 0.f; pq[ct] = 0.f; }
#pragma unroll
  for (int rt = 0; rt < 2; rt++)
#pragma unroll
    for (int rr = 0; rr < 4; rr++) {
      const int r2 = rb + rt * 16 + quad * 4 + rr;
      if (r2 < M) {
#pragma unroll
        for (int ct = 0; ct < 6; ct++) {
          float v = acc[rt][ct][rr];
          ps[ct] += v;
          pq[ct] += v * v;
        }
      }
    }
  float* bnp = (float*)(smem + 32768);  // [2][4][96] wave partials
#pragma unroll
  for (int ct = 0; ct < 6; ct++) {
    float s1 = ps[ct], s2 = pq[ct];
    s1 += __shfl_xor(s1, 16);
    s2 += __shfl_xor(s2, 16);
    s1 += __shfl_xor(s1, 32);
    s2 += __shfl_xor(s2, 32);
    if (quad == 0) {
      bnp[wave * 96 + ct * 16 + m] = s1;
      bnp[384 + wave * 96 + ct * 16 + m] = s2;
    }
  }

  // per-wave LDS transpose (same-wave ds ordering) -> contiguous bf16x8
  // stores (task-major: 64 lanes cover 1024B of consecutive rows/iter)
  float(*trw)[98] = (float(*)[98])(smem + wave * (16 * 98 * 4));
#pragma unroll
  for (int rt = 0; rt < 2; rt++) {
#pragma unroll
    for (int ct = 0; ct < 6; ct++)
#pragma unroll
      for (int rr = 0; rr < 4; rr++)
        trw[quad * 4 + rr][ct * 16 + m] = acc[rt][ct][rr];
#pragma unroll
    for (int it = 0; it < 3; it++) {
      const int task = it * 64 + lane;   // 192 tasks = 16 rows x 12 chunks
      const int row = task / 12;
      const int ch = task - row * 12;
      const int r2 = rb + rt * 16 + row;
      if (r2 < M) {
        bf16x8 o;
#pragma unroll
        for (int j = 0; j < 8; j++) o[j] = (bf16)trw[row][ch * 8 + j];
        *(bf16x8*)(accb + (size_t)r2 * HIDC + ch * 8) = o;
      }
    }
  }

  __syncthreads();  // bnp partials visible
  if (tid < 192) {  // 96 sums + 96 sumsqs, one atomic each
    const int which = tid / 96;           // 0: sum, 1: sumsq
    const int c = tid - which * 96;
    const float* basep = bnp + which * 384;
    float s = basep[c] + basep[96 + c] + basep[192 + c] + basep[288 + c];
    atomicAdd(bnsum + which * 96 + c, s);
  }
}

// ---------------------------------------------------------------------------
// K6: fused linear + devoxelize + residual:
//   phase 1: lin = hx @ W_lin + b_lin via MFMA -> LDS tile (128x96 bf16);
//            cw/cidx for the block's 128 points staged to LDS in one
//            coalesced pass (kills the 12x re-read per point).
//   phase 2: out[p] = lin[p] + sum_k w[p,k] * relu(bn(accb[cidx[p,k]]))
//            with bf16 acc gathers (16B/corner-group) + LDS-resident
//            scale/shift finalized per block from raw bnsum.
// ---------------------------------------------------------------------------
__launch_bounds__(256, 4)
__global__ void k_linout(const float* __restrict__ hid, const float* __restrict__ qry,
                         const bf16* __restrict__ wlpack, const float* __restrict__ blin,
                         const bf16* __restrict__ accb, const float* __restrict__ bnsum,
                         const float* __restrict__ gamma, const float* __restrict__ beta,
                         const float* __restrict__ cw, const int* __restrict__ cidx,
                         float* __restrict__ out, int Npts, int M) {
  __shared__ __align__(16) bf16 linT[128][HIDC];
  __shared__ __align__(16) float cwT[128][8];
  __shared__ __align__(16) int ciT[128][8];
  __shared__ float ssc[96], ssh[96];
  const int tid = threadIdx.x;
  const int pbase = blockIdx.x * 128;
  // BN finalize (cheap, per block)
  if (tid < 96) {
    int c = tid;
    float inv = 1.0f / (float)M;
    float mu = bnsum[c] * inv;
    float var = fmaxf(bnsum[96 + c] * inv - mu * mu, 0.f);
    float sc = gamma[c] * rsqrtf(var + EPSC);
    ssc[c] = sc;
    ssh[c] = beta[c] - mu * sc;
  }
  // stage cw/cidx for the block's 128 points (coalesced f32x4/i32x4)
  {
    int e = tid * 4;                     // 0..1023 elements of 128x8
    int p = pbase + (e >> 3);
    if (p < Npts) {
      *(f32x4*)&cwT[e >> 3][e & 7] = *(const f32x4*)(cw + (size_t)pbase * 8 + e);
      *(i32x4*)&ciT[e >> 3][e & 7] = *(const i32x4*)(cidx + (size_t)pbase * 8 + e);
    }
  }

  // ---- phase 1: MFMA linear into LDS tile ----
  const int wave = tid >> 6;
  const int lane = tid & 63;
  const int m = lane & 15;
  const int quad = lane >> 4;
  const int rb = pbase + wave * 32;

  f32x4 acc[2][6];
#pragma unroll
  for (int rt = 0; rt < 2; rt++)
#pragma unroll
    for (int ct = 0; ct < 6; ct++) {
      f32x4 z = {0.f, 0.f, 0.f, 0.f};
      acc[rt][ct] = z;
    }

  int prow[2];
#pragma unroll
  for (int rt = 0; rt < 2; rt++) {
    int r = rb + rt * 16 + m;
    prow[rt] = (r < Npts) ? r : (Npts - 1);
  }
  const char* wp = (const char*)wlpack;
#pragma unroll
  for (int kc = 0; kc < 6; kc++) {
    const float* srcA = (kc < 3) ? (hid + kc * 32) : (qry + (kc - 3) * 32);
    bf16x8 af[2];
#pragma unroll
    for (int rt = 0; rt < 2; rt++) {
      const float* pA = srcA + (size_t)prow[rt] * HIDC + quad * 8;
      f32x4 lo = *(const f32x4*)pA;
      f32x4 hi = *(const f32x4*)(pA + 4);
#pragma unroll
      for (int j = 0; j < 4; j++) {
        af[rt][j] = (bf16)lo[j];
        af[rt][4 + j] = (bf16)hi[j];
      }
    }
    const int half = (kc >= 3) ? 1 : 0;
    const int kcl = kc - half * 3;
#pragma unroll
    for (int ct = 0; ct < 6; ct++) {
      bf16x8 bfm = *(const bf16x8*)(wp + (size_t)half * STG_B +
                                    (size_t)((kcl * 6 + ct) * 64 + lane) * 16);
#pragma unroll
      for (int rt = 0; rt < 2; rt++)
        acc[rt][ct] = __builtin_amdgcn_mfma_f32_16x16x32_bf16(af[rt], bfm, acc[rt][ct], 0, 0, 0);
    }
  }
  float bl[6];
#pragma unroll
  for (int ct = 0; ct < 6; ct++) bl[ct] = blin[ct * 16 + m];
  // store fragments to LDS tile (local row = wave*32 + rt*16 + quad*4 + rr)
#pragma unroll
  for (int rt = 0; rt < 2; rt++)
#pragma unroll
    for (int rr = 0; rr < 4; rr++) {
      const int lr = wave * 32 + rt * 16 + quad * 4 + rr;
#pragma unroll
      for (int ct = 0; ct < 6; ct++)
        linT[lr][ct * 16 + m] = (bf16)(acc[rt][ct][rr] + bl[ct]);
    }
  __syncthreads();

  // ---- phase 2: per (point, 8-ch group) gather-add, write out ----
#pragma unroll
  for (int it = 0; it < 6; it++) {
    int task = it * 256 + tid;          // 128*12 = 1536 tasks
    int lp = task / 12;
    int g = task - lp * 12;
    int p = pbase + lp;
    if (p < Npts) {
      float a[8];
      bf16x8 lv = *(const bf16x8*)&linT[lp][g * 8];
#pragma unroll
      for (int j = 0; j < 8; j++) a[j] = (float)lv[j];
#pragma unroll
      for (int k = 0; k < 8; k++) {
        int idx = ciT[lp][k];
        float wk = cwT[lp][k];
        bf16x8 v = *(const bf16x8*)(accb + (size_t)idx * HIDC + g * 8);
#pragma unroll
        for (int j = 0; j < 8; j++)
          a[j] += wk * fmaxf((float)v[j] * ssc[g * 8 + j] + ssh[g * 8 + j], 0.f);
      }
      float* op = out + (size_t)p * HIDC + g * 8;
      f32x4 s0, s1;
#pragma unroll
      for (int j = 0; j < 4; j++) { s0[j] = a[j]; s1[j] = a[4 + j]; }
      *(f32x4*)op = s0;
      *(f32x4*)(op + 4) = s1;
    }
  }
}

// ---------------------------------------------------------------------------
extern "C" void kernel_launch(void* const* d_in, const int* in_sizes, int n_in,
                              void* d_out, int out_size, void* d_ws, size_t ws_size,
                              hipStream_t stream) {
  const float* hid = (const float*)d_in[0];
  const float* qry = (const float*)d_in[1];
  const float* Wc = (const float*)d_in[2];
  const float* gamma = (const float*)d_in[3];
  const float* beta = (const float*)d_in[4];
  const float* Wl = (const float*)d_in[5];
  const float* blin = (const float*)d_in[6];
  const float* cw = (const float*)d_in[7];
  const int* seg = (const int*)d_in[8];
  const int* nbr = (const int*)d_in[9];
  const int* cidx = (const int*)d_in[10];
  float* out = (float*)d_out;
  const int Npts = in_sizes[0] / HIDC;
  const int M = in_sizes[9] / 27;

  // ---- workspace layout ----
  // [cnt | bnsum]  <- single memset
  // region A: accb bf16 [M+1,96] (K3..linout; row M read only with w=0)
  // region B: vpad bf16 [M+1,192]
  char* ws = (char*)d_ws;
  size_t cur = 0;
  auto alloc = [&](size_t b) { size_t o = cur; cur = (cur + b + 255) & ~(size_t)255; return o; };
  size_t o_cnt = alloc((size_t)M * 4);
  size_t o_bn = alloc(192 * 4);
  size_t zend = cur;  // memset range [0, zend): cnt + bnsum
  size_t o_ptr = alloc((size_t)M * 4);
  size_t o_cur = alloc((size_t)M * 4);
  size_t o_pl = alloc((size_t)Npts * 4);
  size_t o_bs = alloc(1024 * 4);
  size_t o_A = alloc((size_t)(M + 1) * HIDC * 2);
  size_t o_B = alloc((size_t)(M + 1) * CINC * 2);
  size_t o_wpack = alloc((size_t)56 * STG_B);
  (void)ws_size; (void)n_in; (void)out_size;

  int* cnt = (int*)(ws + o_cnt);
  float* bnsum = (float*)(ws + o_bn);
  int* ptr = (int*)(ws + o_ptr);
  int* cursor = (int*)(ws + o_cur);
  int* plist = (int*)(ws + o_pl);
  int* bsum = (int*)(ws + o_bs);
  bf16* accb = (bf16*)(ws + o_A);
  bf16* vpad = (bf16*)(ws + o_B);
  bf16* wpack = (bf16*)(ws + o_wpack);
  bf16* wlpack = (bf16*)(ws + o_wpack + (size_t)54 * STG_B);

  // zero cnt + bnsum (adjacent at front; ws poisoned 0xAA each call)
  hipMemsetAsync(ws, 0, zend, stream);

  int totalRepack = 28 * 18432;
  k_repack<<<(totalRepack + 255) / 256, 256, 0, stream>>>(Wc, Wl, wpack, totalRepack);

  // voxelize: count -> scan -> scatter -> gather-mean
  int nb = (M + 255) / 256;
  k_count<<<(Npts + 255) / 256, 256, 0, stream>>>(seg, cnt, Npts);
  k_bsum<<<nb, 256, 0, stream>>>(cnt, bsum, M);
  k_bscan<<<1, 1024, 0, stream>>>(bsum, nb);
  k_ptr<<<nb, 256, 0, stream>>>(cnt, bsum, ptr, cursor, M);
  k_scatter<<<(Npts + 255) / 256, 256, 0, stream>>>(seg, cursor, plist, Npts);
  k_gmean<<<(((M + 1) * 24) + 255) / 256, 256, 0, stream>>>(hid, qry, ptr, cnt, plist, vpad, M);

  int nblk = (M + 127) / 128;
  int nper = (nblk + 7) / 8;
  k_conv<<<nper * 8, 256, 0, stream>>>(vpad, nbr, wpack, accb, bnsum, M, nblk, nper);
  k_linout<<<(Npts + 127) / 128, 256, 0, stream>>>(hid, qry, wlpack, blin, accb, bnsum,
                                                   gamma, beta, cw, cidx, out, Npts, M);
}